// Round 3
// baseline (536.558 us; speedup 1.0000x reference)
//
#include <hip/hip_runtime.h>
#include <hip/hip_fp16.h>

#define D 1024
#define LOG2D 10
#define S_LEN 4096
#define BATCH 4
#define NROWS (BATCH * S_LEN) /* 16384 */
#define PI_F 3.14159265358979323846f

typedef _Float16 f16x8 __attribute__((ext_vector_type(8)));
typedef float f32x4 __attribute__((ext_vector_type(4)));

__device__ __forceinline__ float2 cmul(float2 a, float2 b) {
    return make_float2(a.x * b.x - a.y * b.y, a.x * b.y + a.y * b.x);
}

__device__ __forceinline__ float fast_tanh(float v) {
    float e = __expf(2.0f * v);
    return 1.0f - 2.0f * __builtin_amdgcn_rcpf(e + 1.0f);
}

__device__ __forceinline__ void g2lds16(const void* g, void* l) {
    __builtin_amdgcn_global_load_lds(
        (const __attribute__((address_space(1))) unsigned int*)g,
        (__attribute__((address_space(3))) unsigned int*)l, 16, 0, 0);
}

// ---------------- fp32 -> fp16 conversion (x and the 4 weight matrices) ----
__global__ __launch_bounds__(256) void convert_all(
    const float* __restrict__ x,
    const float* __restrict__ w0, const float* __restrict__ w1,
    const float* __restrict__ w2, const float* __restrict__ w3,
    __half* __restrict__ xh,
    __half* __restrict__ h0, __half* __restrict__ h1,
    __half* __restrict__ h2, __half* __restrict__ h3)
{
    const int b = blockIdx.x;
    const float* s;
    __half* d;
    int li;
    if (b < 16384) { s = x; d = xh; li = b; }
    else {
        int t = b - 16384;
        int r = t >> 10;
        li = t & 1023;
        s = (r == 0) ? w0 : (r == 1) ? w1 : (r == 2) ? w2 : w3;
        d = (r == 0) ? h0 : (r == 1) ? h1 : (r == 2) ? h2 : h3;
    }
    const int idx = li * 256 + threadIdx.x;  // float4 index
    float4 v = ((const float4*)s)[idx];
    __half2 lo = __floats2half2_rn(v.x, v.y);
    __half2 hi = __floats2half2_rn(v.z, v.w);
    ((__half2*)d)[2 * idx + 0] = lo;
    ((__half2*)d)[2 * idx + 1] = hi;
}

// ------- Fused dual MFMA GEMM: O{0,1} = tanh(Xh * W{0,1}^T + b{0,1}) -------
// 128x128 tile, BK=64, 512 threads (8 waves, 2m x 4n), 3-slot LDS ring
// (144 KiB). Iteration t computes slot t%3 while issuing the 6 g2lds for
// K-tile t+2 into the slot freed at t-1's barrier. Boundary = vmcnt(6) +
// s_barrier -> staging loads NEVER drain to 0 in the main loop (T4).
// Chunk-XOR LDS swizzle (slot q^(row&7)) keeps ds_read_b128 conflict-free.
__global__ __launch_bounds__(512, 1) void gemm_mfma2(
    const __half* __restrict__ Xh,
    const __half* __restrict__ W0, const float* __restrict__ b0, __half* __restrict__ O0,
    const __half* __restrict__ W1, const float* __restrict__ b1, __half* __restrict__ O1)
{
    const int idx = blockIdx.x;
    const int xcd = idx & 7;
    const int j = idx >> 3;           // 0..127
    const int n0 = (j & 7) * 128;
    const int m0 = (xcd * 16 + (j >> 3)) * 128;

    __shared__ __align__(16) __half As[3][128 * 64];
    __shared__ __align__(16) __half B0s[3][128 * 64];
    __shared__ __align__(16) __half B1s[3][128 * 64];

    const int tid = threadIdx.x;
    const int wave = tid >> 6;        // 0..7
    const int lane = tid & 63;

    // staging: one g2lds = 64 lanes x 16B = 8 rows x 8 chunks.
    // lane -> row (lane>>3), LDS chunk slot (lane&7); global chunk =
    // slot ^ (row&7) = (lane&7) ^ (lane>>3).
    const int srow = lane >> 3;
    const int schunk = (lane & 7) ^ srow;

    // each of the 8 waves stages 16 rows (2 g2lds) of each matrix
    const __half* gA[2];
    const __half* gB0[2];
    const __half* gB1[2];
    int loff[2];
#pragma unroll
    for (int c = 0; c < 2; ++c) {
        const int rbase = wave * 16 + c * 8;
        gA[c]  = Xh + (size_t)(m0 + rbase + srow) * 1024 + schunk * 8;
        gB0[c] = W0 + (size_t)(n0 + rbase + srow) * 1024 + schunk * 8;
        gB1[c] = W1 + (size_t)(n0 + rbase + srow) * 1024 + schunk * 8;
        loff[c] = rbase * 64;                         // half units
    }

    const int wm = (wave & 1) * 64;   // 2-way m split
    const int wn = (wave >> 1) * 32;  // 4-way n split
    const int quad = lane >> 4;
    const int l15 = lane & 15;

    // frag read offsets: row R, k-slice kk: chunk c=(kk<<2)|quad at
    // slot c ^ (R&7); R&7 = l15&7 (wm, wn, i*16 are multiples of 8).
    int aoff[2][4], boff[2][2];
#pragma unroll
    for (int kk = 0; kk < 2; ++kk) {
#pragma unroll
        for (int i = 0; i < 4; ++i) {
            const int Ra = wm + i * 16 + l15;
            aoff[kk][i] = Ra * 64 + ((((kk << 2) | quad)) ^ (l15 & 7)) * 8;
        }
#pragma unroll
        for (int i = 0; i < 2; ++i) {
            const int Rb = wn + i * 16 + l15;
            boff[kk][i] = Rb * 64 + ((((kk << 2) | quad)) ^ (l15 & 7)) * 8;
        }
    }

    f32x4 acc0[4][2], acc1[4][2];
#pragma unroll
    for (int i = 0; i < 4; ++i)
#pragma unroll
        for (int jj = 0; jj < 2; ++jj) {
            acc0[i][jj] = (f32x4){0.f, 0.f, 0.f, 0.f};
            acc1[i][jj] = (f32x4){0.f, 0.f, 0.f, 0.f};
        }

    // prologue: stage K-tiles 0 and 1 (6 loads each); wait for tile 0 only
    {
#pragma unroll
        for (int c = 0; c < 2; ++c) {
            g2lds16(gA[c],       &As[0][loff[c]]);
            g2lds16(gB0[c],      &B0s[0][loff[c]]);
            g2lds16(gB1[c],      &B1s[0][loff[c]]);
        }
#pragma unroll
        for (int c = 0; c < 2; ++c) {
            g2lds16(gA[c] + 64,  &As[1][loff[c]]);
            g2lds16(gB0[c] + 64, &B0s[1][loff[c]]);
            g2lds16(gB1[c] + 64, &B1s[1][loff[c]]);
        }
    }
    asm volatile("s_waitcnt vmcnt(6)" ::: "memory");
    __builtin_amdgcn_s_barrier();

    int slC = 0;   // compute slot (K-tile kt)
    int slS = 2;   // stage slot   (K-tile kt+2)
    for (int kt = 0; kt < 16; ++kt) {
        const int kh2 = (kt + 2) * 64;
        const bool st = (kt < 14);
        const __half* Ac  = &As[slC][0];
        const __half* B0c = &B0s[slC][0];
        const __half* B1c = &B1s[slC][0];

#pragma unroll
        for (int kk = 0; kk < 2; ++kk) {
            // stage half of K-tile kt+2 (3 g2lds) before the ds_reads
            if (st) {
                g2lds16(gA[kk]  + kh2, &As[slS][loff[kk]]);
                g2lds16(gB0[kk] + kh2, &B0s[slS][loff[kk]]);
                g2lds16(gB1[kk] + kh2, &B1s[slS][loff[kk]]);
            }
            f16x8 af[4], bf0[2], bf1[2];
#pragma unroll
            for (int i = 0; i < 4; ++i) af[i] = *(const f16x8*)(Ac + aoff[kk][i]);
#pragma unroll
            for (int jj = 0; jj < 2; ++jj) {
                bf0[jj] = *(const f16x8*)(B0c + boff[kk][jj]);
                bf1[jj] = *(const f16x8*)(B1c + boff[kk][jj]);
            }
            __builtin_amdgcn_s_setprio(1);
#pragma unroll
            for (int i = 0; i < 4; ++i)
#pragma unroll
                for (int jj = 0; jj < 2; ++jj) {
                    acc0[i][jj] = __builtin_amdgcn_mfma_f32_16x16x32_f16(af[i], bf0[jj], acc0[i][jj], 0, 0, 0);
                    acc1[i][jj] = __builtin_amdgcn_mfma_f32_16x16x32_f16(af[i], bf1[jj], acc1[i][jj], 0, 0, 0);
                }
            __builtin_amdgcn_s_setprio(0);
        }

        if (kt < 15) {
            if (st) { asm volatile("s_waitcnt vmcnt(6)" ::: "memory"); }
            else    { asm volatile("s_waitcnt vmcnt(0)" ::: "memory"); }
            __builtin_amdgcn_s_barrier();
        }
        slC = (slC == 2) ? 0 : slC + 1;
        slS = (slS == 2) ? 0 : slS + 1;
    }

    // epilogue: C/D frag mapping col=lane&15, row=quad*4+reg
#pragma unroll
    for (int jj = 0; jj < 2; ++jj) {
        const int n = n0 + wn + jj * 16 + l15;
        const float bv0 = b0[n];
        const float bv1 = b1[n];
#pragma unroll
        for (int i = 0; i < 4; ++i) {
            const int mbase = m0 + wm + i * 16 + quad * 4;
#pragma unroll
            for (int r = 0; r < 4; ++r) {
                O0[(size_t)(mbase + r) * 1024 + n] = __float2half(fast_tanh(acc0[i][jj][r] + bv0));
                O1[(size_t)(mbase + r) * 1024 + n] = __float2half(fast_tanh(acc1[i][jj][r] + bv1));
            }
        }
    }
}

// ================= register FFT-32 building blocks (proven) ================
__device__ constexpr int br5(int i) {
    return ((i & 1) << 4) | ((i & 2) << 2) | (i & 4) | ((i & 8) >> 2) | ((i & 16) >> 4);
}

// W32^k twiddles as compile-time constants (k static after unroll).
// INV=0: e^{-2pi i k/32}; INV=1: conjugate.
template<int INV>
__device__ __forceinline__ float2 w32c(int k) {
    constexpr float C[16] = {
        1.0f, 0.98078528f, 0.92387953f, 0.83146961f,
        0.70710678f, 0.55557023f, 0.38268343f, 0.19509032f,
        0.0f, -0.19509032f, -0.38268343f, -0.55557023f,
        -0.70710678f, -0.83146961f, -0.92387953f, -0.98078528f};
    constexpr float Sn[16] = {
        0.0f, 0.19509032f, 0.38268343f, 0.55557023f,
        0.70710678f, 0.83146961f, 0.92387953f, 0.98078528f,
        1.0f, 0.98078528f, 0.92387953f, 0.83146961f,
        0.70710678f, 0.55557023f, 0.38268343f, 0.19509032f};
    return make_float2(C[k], INV ? Sn[k] : -Sn[k]);
}

// In-register 32-point FFT. Input in registers bit-reversed, output natural.
template<int INV>
__device__ __forceinline__ void fft32(float2* z) {
#pragma unroll
    for (int s = 0; s < 5; ++s) {
#pragma unroll
        for (int j = 0; j < 16; ++j) {
            const int half = 1 << s;
            const int blk = j >> s;
            const int off = j & (half - 1);
            const int i0 = (blk << (s + 1)) + off;
            const int i1 = i0 + half;
            const float2 w = w32c<INV>(off << (4 - s));
            const float2 v = cmul(z[i1], w);
            z[i1] = make_float2(z[i0].x - v.x, z[i0].y - v.y);
            z[i0] = make_float2(z[i0].x + v.x, z[i0].y + v.y);
        }
    }
}

// ================= register-FFT bind kernel (forward only) =================
// 32 lanes per row, 8 rows per group, 8 groups per 256-thread block.
// Intra-wave LDS transposes (groups are half-waves) -> ZERO barriers;
// DS pipe is in-order within a wave. Pad 35 keeps all rounds <=2-way.
#define BGRP 8
#define BROWS 8
__global__ __launch_bounds__(256) void bind_accum_kernel(
    const __half* __restrict__ K, const __half* __restrict__ V, float2* __restrict__ Fs)
{
    __shared__ float2 T[BGRP][35 * 32];
    const int tid = threadIdx.x;
    const int grp = tid >> 5;
    const int t = tid & 31;
    const int row0 = blockIdx.x * (BGRP * BROWS) + grp * BROWS;
    const int b = row0 >> 12;
    float2* Tr = T[grp];

    float sn_, cs_;
    __sincosf((PI_F / 512.0f) * (float)t, &sn_, &cs_);
    const float2 w1 = make_float2(cs_, -sn_);

    float2 acc[32];
#pragma unroll
    for (int i = 0; i < 32; ++i) acc[i] = make_float2(0.f, 0.f);

    f16x8 kb[2][4], vb[2][4];
    {
        const __half* Kr = K + ((size_t)row0 << 10) + t * 32;
        const __half* Vr = V + ((size_t)row0 << 10) + t * 32;
#pragma unroll
        for (int c = 0; c < 4; ++c) {
            kb[0][c] = *(const f16x8*)(Kr + c * 8);
            vb[0][c] = *(const f16x8*)(Vr + c * 8);
        }
    }

#pragma unroll
    for (int r = 0; r < BROWS; ++r) {
        // prefetch next row's K,V while computing this one
        if (r + 1 < BROWS) {
            const __half* Kr = K + ((size_t)(row0 + r + 1) << 10) + t * 32;
            const __half* Vr = V + ((size_t)(row0 + r + 1) << 10) + t * 32;
#pragma unroll
            for (int c = 0; c < 4; ++c) {
                kb[(r + 1) & 1][c] = *(const f16x8*)(Kr + c * 8);
                vb[(r + 1) & 1][c] = *(const f16x8*)(Vr + c * 8);
            }
        }
        // input transpose: lane t holds n = 32t + i -> Tr[row i][col t];
        // lane t then needs z[n1] = x[32*n1 + t] = Tr[row t][col n1].
#pragma unroll
        for (int c = 0; c < 4; ++c)
#pragma unroll
            for (int e = 0; e < 8; ++e) {
                const int i = c * 8 + e;
                Tr[35 * i + t] = make_float2((float)kb[r & 1][c][e],
                                             (float)vb[r & 1][c][e]);
            }
        float2 z[32];
#pragma unroll
        for (int n1 = 0; n1 < 32; ++n1) z[br5(n1)] = Tr[35 * t + n1];
        fft32<0>(z);                 // A[k1] over n1
        {
            float2 tw = make_float2(1.0f, 0.0f);
#pragma unroll
            for (int k1 = 0; k1 < 32; ++k1) { z[k1] = cmul(z[k1], tw); tw = cmul(tw, w1); }
        }
#pragma unroll
        for (int k1 = 0; k1 < 32; ++k1) Tr[35 * k1 + t] = z[k1];
#pragma unroll
        for (int n2 = 0; n2 < 32; ++n2) z[br5(n2)] = Tr[35 * t + n2];
        fft32<0>(z);                 // Z[t + 32*k2]
#pragma unroll
        for (int k2 = 0; k2 < 32; ++k2) Tr[35 * k2 + t] = z[k2];
        const int mc = (32 - t) & 31;
        const int me = (t == 0) ? 1 : 0;
#pragma unroll
        for (int k2 = 0; k2 < 32; ++k2) {
            const int ma = (31 - k2 + me) & 31;
            float2 Zc = Tr[35 * ma + mc];
            Zc.y = -Zc.y;              // conj(Z[1024-j])
            const float2 Zt = z[k2];   // Z[j], j = t + 32*k2
            const float2 Fk = make_float2(0.5f * (Zt.x + Zc.x), 0.5f * (Zt.y + Zc.y));
            const float2 Fv = make_float2(0.5f * (Zt.y - Zc.y), -0.5f * (Zt.x - Zc.x));
            const float2 P = cmul(Fk, Fv);
            acc[k2].x += P.x; acc[k2].y += P.y;
        }
    }
    float2* FsB = Fs + ((size_t)b << 10);
#pragma unroll
    for (int k2 = 0; k2 < 32; ++k2) {
        atomicAdd(&FsB[(k2 << 5) + t].x, acc[k2].x);
        atomicAdd(&FsB[(k2 << 5) + t].y, acc[k2].y);
    }
}

// ===================== register-FFT retrieve kernel ========================
#define RETR_ROWS 4
__global__ __launch_bounds__(128) void retrieve_kernel(
    const __half* __restrict__ Q, const __half* __restrict__ R,
    const float2* __restrict__ Fs, const float* __restrict__ x, float* __restrict__ out)
{
    // per-row transpose buffer, pad 33 (row stride 33 float2) -> conflict-free
    __shared__ __align__(16) float2 T[RETR_ROWS][33 * 32];
    const int tid = threadIdx.x;
    const int lr = tid >> 5;     // local row 0..3
    const int t  = tid & 31;     // lane within row = n2 / k1 / n1 role
    const int row = blockIdx.x * RETR_ROWS + lr;
    const int b = row >> 12;
    const size_t base = (size_t)row << 10;
    float2* Tr = T[lr];

    // ---- load z[n1] = Q + i*R at n = 32*n1 + t, bit-reversed into regs ----
    float2 z[32];
#pragma unroll
    for (int n1 = 0; n1 < 32; ++n1) {
        const int g = (n1 << 5) + t;
        z[br5(n1)] = make_float2(__half2float(Q[base + g]),
                                 __half2float(R[base + g]));
    }
    fft32<0>(z);                     // A[k1] over n1 (natural order)

    // ---- middle twiddle W1024^{-t*k1}: sincos once + recurrence ----------
    float sn_, cs_;
    __sincosf((PI_F / 512.0f) * (float)t, &sn_, &cs_);
    {
        const float2 w1 = make_float2(cs_, -sn_);
        float2 tw = make_float2(1.0f, 0.0f);
#pragma unroll
        for (int k1 = 0; k1 < 32; ++k1) { z[k1] = cmul(z[k1], tw); tw = cmul(tw, w1); }
    }

    // ---- transpose #1: write [k1][t], read [t][n2] (bitrev into regs) ----
#pragma unroll
    for (int k1 = 0; k1 < 32; ++k1) Tr[33 * k1 + t] = z[k1];
    __syncthreads();
#pragma unroll
    for (int n2 = 0; n2 < 32; ++n2) z[br5(n2)] = Tr[33 * t + n2];
    fft32<0>(z);                     // z[k2] = Z[t + 32*k2]
    __syncthreads();                 // WAR: transpose reads done

    // ---- mirror round: Z -> LDS [k2][t]; read Z[1024-j] from mirror ------
#pragma unroll
    for (int k2 = 0; k2 < 32; ++k2) Tr[33 * k2 + t] = z[k2];
    __syncthreads();

    float2 h[32];
    const float2* FsB = Fs + ((size_t)b << 10);
    const int mc = (32 - t) & 31;
    const int me = (t == 0) ? 1 : 0;   // t=0 mirrors onto itself, shifted row
#pragma unroll
    for (int k2 = 0; k2 < 32; ++k2) {
        const int ma = (31 - k2 + me) & 31;
        float2 Zc = Tr[33 * ma + mc];
        Zc.y = -Zc.y;                  // conj(Z[1024-j])
        const float2 Zt = z[k2];       // Z[j], j = t + 32*k2
        const float2 Fq = make_float2(0.5f * (Zt.x + Zc.x), 0.5f * (Zt.y + Zc.y));
        const float2 Fr = make_float2(0.5f * (Zt.y - Zc.y), -0.5f * (Zt.x - Zc.x));
        const float2 g2 = make_float2(Fq.x - (Fr.x * Fr.x + Fr.y * Fr.y), -Fq.y);
        const float2 Ff = FsB[(k2 << 5) + t];
        h[br5(k2)] = cmul(Ff, g2);     // H[j], bitrev for inverse stage 1
    }

    // ---- inverse: same distribution (k = t mod 32) -> register-local -----
    fft32<1>(h);                     // over k1
    {
        const float2 w1c = make_float2(cs_, sn_);   // W1024^{+n1*t}
        float2 tw = make_float2(1.0f, 0.0f);
#pragma unroll
        for (int n1 = 0; n1 < 32; ++n1) { h[n1] = cmul(h[n1], tw); tw = cmul(tw, w1c); }
    }
    __syncthreads();                 // WAR: mirror reads done before overwrite
#pragma unroll
    for (int n1 = 0; n1 < 32; ++n1) Tr[33 * n1 + t] = h[n1];
    __syncthreads();
#pragma unroll
    for (int k2 = 0; k2 < 32; ++k2) h[br5(k2)] = Tr[33 * t + k2];
    fft32<1>(h);                     // h[n2] = y[t + 32*n2] (unscaled)

    // ---- out = x + real(y)/1024, coalesced (32 consecutive lanes) --------
    const float* xr = x + base;
    float* outr = out + base;
#pragma unroll
    for (int n2 = 0; n2 < 32; ++n2) {
        const int g = (n2 << 5) + t;
        outr[g] = xr[g] + h[n2].x * (1.0f / 1024.0f);
    }
}

extern "C" void kernel_launch(void* const* d_in, const int* in_sizes, int n_in,
                              void* d_out, int out_size, void* d_ws, size_t ws_size,
                              hipStream_t stream) {
    const float* x  = (const float*)d_in[0];
    const float* Wq = (const float*)d_in[1];
    const float* bq = (const float*)d_in[2];
    const float* Wk = (const float*)d_in[3];
    const float* bk = (const float*)d_in[4];
    const float* Wv = (const float*)d_in[5];
    const float* bv = (const float*)d_in[6];
    const float* Wr = (const float*)d_in[7];
    const float* br = (const float*)d_in[8];
    float* out = (float*)d_out;

    // ws: P0 (32MB fp16), P1 (32MB fp16), Fs (32KB)
    __half* P0 = (__half*)d_ws;
    __half* P1 = (__half*)((char*)d_ws + (size_t)NROWS * D * 2);
    float2* Fs = (float2*)((char*)d_ws + (size_t)NROWS * D * 4);

    // d_out doubles as fp16 scratch until the final kernel rewrites all of it
    __half* Xh  = (__half*)d_out;
    __half* Whk = (__half*)d_out + (size_t)16 * 1024 * 1024;
    __half* Whv = Whk + (size_t)1024 * 1024;
    __half* Whq = Whv + (size_t)1024 * 1024;
    __half* Whr = Whq + (size_t)1024 * 1024;

    convert_all<<<16384 + 4 * 1024, 256, 0, stream>>>(
        x, Wk, Wv, Wq, Wr, Xh, Whk, Whv, Whq, Whr);

    hipMemsetAsync(Fs, 0, (size_t)BATCH * D * sizeof(float2), stream);

    gemm_mfma2<<<1024, 512, 0, stream>>>(Xh, Whk, bk, P0, Whv, bv, P1);
    bind_accum_kernel<<<NROWS / (BGRP * BROWS), 256, 0, stream>>>(P0, P1, Fs);
    gemm_mfma2<<<1024, 512, 0, stream>>>(Xh, Whq, bq, P0, Whr, br, P1);
    retrieve_kernel<<<NROWS / RETR_ROWS, 128, 0, stream>>>(P0, P1, Fs, x, out);
}

// Round 4
// 536.449 us; speedup vs baseline: 1.0002x; 1.0002x over previous
//
#include <hip/hip_runtime.h>
#include <hip/hip_fp16.h>

#define D 1024
#define LOG2D 10
#define S_LEN 4096
#define BATCH 4
#define NROWS (BATCH * S_LEN) /* 16384 */
#define PI_F 3.14159265358979323846f

typedef _Float16 f16x8 __attribute__((ext_vector_type(8)));
typedef float f32x4 __attribute__((ext_vector_type(4)));

__device__ __forceinline__ float2 cmul(float2 a, float2 b) {
    return make_float2(a.x * b.x - a.y * b.y, a.x * b.y + a.y * b.x);
}

__device__ __forceinline__ float fast_tanh(float v) {
    float e = __expf(2.0f * v);
    return 1.0f - 2.0f * __builtin_amdgcn_rcpf(e + 1.0f);
}

__device__ __forceinline__ void g2lds16(const void* g, void* l) {
    __builtin_amdgcn_global_load_lds(
        (const __attribute__((address_space(1))) unsigned int*)g,
        (__attribute__((address_space(3))) unsigned int*)l, 16, 0, 0);
}

// ---------------- fp32 -> fp16 conversion (x and the 4 weight matrices) ----
__global__ __launch_bounds__(256) void convert_all(
    const float* __restrict__ x,
    const float* __restrict__ w0, const float* __restrict__ w1,
    const float* __restrict__ w2, const float* __restrict__ w3,
    __half* __restrict__ xh,
    __half* __restrict__ h0, __half* __restrict__ h1,
    __half* __restrict__ h2, __half* __restrict__ h3)
{
    const int b = blockIdx.x;
    const float* s;
    __half* d;
    int li;
    if (b < 16384) { s = x; d = xh; li = b; }
    else {
        int t = b - 16384;
        int r = t >> 10;
        li = t & 1023;
        s = (r == 0) ? w0 : (r == 1) ? w1 : (r == 2) ? w2 : w3;
        d = (r == 0) ? h0 : (r == 1) ? h1 : (r == 2) ? h2 : h3;
    }
    const int idx = li * 256 + threadIdx.x;  // float4 index
    float4 v = ((const float4*)s)[idx];
    __half2 lo = __floats2half2_rn(v.x, v.y);
    __half2 hi = __floats2half2_rn(v.z, v.w);
    ((__half2*)d)[2 * idx + 0] = lo;
    ((__half2*)d)[2 * idx + 1] = hi;
}

// ------- Fused dual MFMA GEMM (round-1 proven structure, 89-91 us) --------
// O = {tanh(Xh*W0^T+b0), tanh(Xh*W1^T+b1)} stored INTERLEAVED as __half2.
// 128x128 tile, BK=64 (16 k-tiles, 64 MFMA per barrier pair), 256 thr.
// LDS [row][64] halves, 8 chunks of 16B per row, chunk q stored at slot
// q ^ (row&7) -> global_load_lds stays lane-contiguous, ds_read_b128 2-way max.
// XCD-swizzled block mapping for L2 locality.
__global__ __launch_bounds__(256, 2) void gemm_mfma2(
    const __half* __restrict__ Xh,
    const __half* __restrict__ W0, const float* __restrict__ b0,
    const __half* __restrict__ W1, const float* __restrict__ b1,
    __half2* __restrict__ KV)
{
    const int idx = blockIdx.x;
    const int xcd = idx & 7;
    const int j = idx >> 3;           // 0..127
    const int n0 = (j & 7) * 128;
    const int m0 = (xcd * 16 + (j >> 3)) * 128;

    __shared__ __align__(16) __half As[128 * 64];
    __shared__ __align__(16) __half B0s[128 * 64];
    __shared__ __align__(16) __half B1s[128 * 64];

    const int tid = threadIdx.x;
    const int wave = tid >> 6;
    const int lane = tid & 63;

    // staging: one g2lds = 64 lanes x 16B = 8 rows x 8 chunks.
    const int srow = lane >> 3;
    const int schunk = (lane & 7) ^ (lane >> 3);

    const __half* gA[4];
    const __half* gB0[4];
    const __half* gB1[4];
    int loff[4];
#pragma unroll
    for (int c = 0; c < 4; ++c) {
        const int rbase = wave * 32 + c * 8;         // multiple of 8
        gA[c]  = Xh + (size_t)(m0 + rbase + srow) * 1024 + schunk * 8;
        gB0[c] = W0 + (size_t)(n0 + rbase + srow) * 1024 + schunk * 8;
        gB1[c] = W1 + (size_t)(n0 + rbase + srow) * 1024 + schunk * 8;
        loff[c] = rbase * 64;                         // half units
    }

    const int wm = (wave & 1) * 64;
    const int wn = (wave >> 1) * 64;
    const int quad = lane >> 4;
    const int l15 = lane & 15;

    // frag read offsets: row R, k-slice kk (0/1): chunk c=(kk<<2)|quad at
    // slot c ^ (R&7); R&7 = l15&7 here (wm, i*16 are multiples of 8).
    int aoff[2][4], boff[2][4];
#pragma unroll
    for (int kk = 0; kk < 2; ++kk)
#pragma unroll
        for (int i = 0; i < 4; ++i) {
            const int Ra = wm + i * 16 + l15;
            aoff[kk][i] = Ra * 64 + ((((kk << 2) | quad)) ^ (l15 & 7)) * 8;
            const int Rb = wn + i * 16 + l15;
            boff[kk][i] = Rb * 64 + ((((kk << 2) | quad)) ^ (l15 & 7)) * 8;
        }

    f32x4 acc0[4][4], acc1[4][4];
#pragma unroll
    for (int i = 0; i < 4; ++i)
#pragma unroll
        for (int jj = 0; jj < 4; ++jj) {
            acc0[i][jj] = (f32x4){0.f, 0.f, 0.f, 0.f};
            acc1[i][jj] = (f32x4){0.f, 0.f, 0.f, 0.f};
        }

    for (int kt = 0; kt < 16; ++kt) {
        const int kh = kt * 64;
        __syncthreads();
#pragma unroll
        for (int c = 0; c < 4; ++c) {
            g2lds16(gA[c] + kh,  As  + loff[c]);
            g2lds16(gB0[c] + kh, B0s + loff[c]);
            g2lds16(gB1[c] + kh, B1s + loff[c]);
        }
        __syncthreads();

#pragma unroll
        for (int kk = 0; kk < 2; ++kk) {
            f16x8 af[4], bf0[4], bf1[4];
#pragma unroll
            for (int i = 0; i < 4; ++i) af[i] = *(const f16x8*)(As + aoff[kk][i]);
#pragma unroll
            for (int jj = 0; jj < 4; ++jj) {
                bf0[jj] = *(const f16x8*)(B0s + boff[kk][jj]);
                bf1[jj] = *(const f16x8*)(B1s + boff[kk][jj]);
            }
#pragma unroll
            for (int i = 0; i < 4; ++i)
#pragma unroll
                for (int jj = 0; jj < 4; ++jj) {
                    acc0[i][jj] = __builtin_amdgcn_mfma_f32_16x16x32_f16(af[i], bf0[jj], acc0[i][jj], 0, 0, 0);
                    acc1[i][jj] = __builtin_amdgcn_mfma_f32_16x16x32_f16(af[i], bf1[jj], acc1[i][jj], 0, 0, 0);
                }
        }
    }

    // epilogue: C/D frag mapping col=lane&15, row=quad*4+reg; interleaved pair
#pragma unroll
    for (int jj = 0; jj < 4; ++jj) {
        const int n = n0 + wn + jj * 16 + l15;
        const float bv0 = b0[n];
        const float bv1 = b1[n];
#pragma unroll
        for (int i = 0; i < 4; ++i) {
            const int mbase = m0 + wm + i * 16 + quad * 4;
#pragma unroll
            for (int r = 0; r < 4; ++r) {
                const __half h0 = __float2half(fast_tanh(acc0[i][jj][r] + bv0));
                const __half h1 = __float2half(fast_tanh(acc1[i][jj][r] + bv1));
                KV[(size_t)(mbase + r) * 1024 + n] = __halves2half2(h0, h1);
            }
        }
    }
}

// ================= register FFT-32 building blocks (proven) ================
__device__ constexpr int br5(int i) {
    return ((i & 1) << 4) | ((i & 2) << 2) | (i & 4) | ((i & 8) >> 2) | ((i & 16) >> 4);
}

// W32^k twiddles as compile-time constants (k static after unroll).
// INV=0: e^{-2pi i k/32}; INV=1: conjugate.
template<int INV>
__device__ __forceinline__ float2 w32c(int k) {
    constexpr float C[16] = {
        1.0f, 0.98078528f, 0.92387953f, 0.83146961f,
        0.70710678f, 0.55557023f, 0.38268343f, 0.19509032f,
        0.0f, -0.19509032f, -0.38268343f, -0.55557023f,
        -0.70710678f, -0.83146961f, -0.92387953f, -0.98078528f};
    constexpr float Sn[16] = {
        0.0f, 0.19509032f, 0.38268343f, 0.55557023f,
        0.70710678f, 0.83146961f, 0.92387953f, 0.98078528f,
        1.0f, 0.98078528f, 0.92387953f, 0.83146961f,
        0.70710678f, 0.55557023f, 0.38268343f, 0.19509032f};
    return make_float2(C[k], INV ? Sn[k] : -Sn[k]);
}

// In-register 32-point FFT. Input in registers bit-reversed, output natural.
template<int INV>
__device__ __forceinline__ void fft32(float2* z) {
#pragma unroll
    for (int s = 0; s < 5; ++s) {
#pragma unroll
        for (int j = 0; j < 16; ++j) {
            const int half = 1 << s;
            const int blk = j >> s;
            const int off = j & (half - 1);
            const int i0 = (blk << (s + 1)) + off;
            const int i1 = i0 + half;
            const float2 w = w32c<INV>(off << (4 - s));
            const float2 v = cmul(z[i1], w);
            z[i1] = make_float2(z[i0].x - v.x, z[i0].y - v.y);
            z[i0] = make_float2(z[i0].x + v.x, z[i0].y + v.y);
        }
    }
}

// ================= register-FFT bind kernel (forward only) =================
// Interleaved KV input: lane t loads z[n1] = KV[32*n1 + t] DIRECTLY from
// global (one u32 per point) -> no input LDS transpose, no prefetch regs.
// 32 lanes per row, 8 groups per 256-thread block, BROWS=4 rows/group ->
// 512 blocks, 2 blocks/CU (66 KiB LDS), ~150 VGPR (no spill, cap (256,2)).
// Transposes are intra-wave (group = half-wave): DS pipe is in-order within
// a wave -> no __syncthreads; sched_barrier(0) pins compiler ordering where
// the cross-lane dependency is invisible per-thread.
#define BGRP 8
#define BROWS 4
__global__ __launch_bounds__(256, 2) void bind_accum_kernel(
    const unsigned int* __restrict__ KV, float2* __restrict__ Fs)
{
    __shared__ float2 T[BGRP][33 * 32];
    const int tid = threadIdx.x;
    const int grp = tid >> 5;
    const int t = tid & 31;
    const int row0 = blockIdx.x * (BGRP * BROWS) + grp * BROWS;
    const int b = row0 >> 12;
    float2* Tr = T[grp];

    float sn_, cs_;
    __sincosf((PI_F / 512.0f) * (float)t, &sn_, &cs_);
    const float2 w1 = make_float2(cs_, -sn_);

    float2 acc[32];
#pragma unroll
    for (int i = 0; i < 32; ++i) acc[i] = make_float2(0.f, 0.f);

    const int mc = (32 - t) & 31;
    const int me = (t == 0) ? 1 : 0;

    for (int r = 0; r < BROWS; ++r) {
        const unsigned int* src = KV + ((size_t)(row0 + r) << 10);
        float2 z[32];
#pragma unroll
        for (int n1 = 0; n1 < 32; ++n1) {
            const unsigned int u = src[(n1 << 5) + t];
            const __half2 hv = *(const __half2*)&u;   // {K, V}
            z[br5(n1)] = make_float2(__half2float(hv.x), __half2float(hv.y));
        }
        fft32<0>(z);                 // A[k1] over n1
        {
            float2 tw = make_float2(1.0f, 0.0f);
#pragma unroll
            for (int k1 = 0; k1 < 32; ++k1) { z[k1] = cmul(z[k1], tw); tw = cmul(tw, w1); }
        }
        // transpose: write [k1][t], read [t][n2] (cross-lane, same wave)
#pragma unroll
        for (int k1 = 0; k1 < 32; ++k1) Tr[33 * k1 + t] = z[k1];
        __builtin_amdgcn_sched_barrier(0);
#pragma unroll
        for (int n2 = 0; n2 < 32; ++n2) z[br5(n2)] = Tr[33 * t + n2];
        fft32<0>(z);                 // Z[t + 32*k2]
        // mirror round: Z -> LDS [k2][t]; read conj(Z[1024-j]) cross-lane
#pragma unroll
        for (int k2 = 0; k2 < 32; ++k2) Tr[33 * k2 + t] = z[k2];
        __builtin_amdgcn_sched_barrier(0);
#pragma unroll
        for (int k2 = 0; k2 < 32; ++k2) {
            const int ma = (31 - k2 + me) & 31;
            float2 Zc = Tr[33 * ma + mc];
            Zc.y = -Zc.y;              // conj(Z[1024-j])
            const float2 Zt = z[k2];   // Z[j], j = t + 32*k2
            const float2 Fk = make_float2(0.5f * (Zt.x + Zc.x), 0.5f * (Zt.y + Zc.y));
            const float2 Fv = make_float2(0.5f * (Zt.y - Zc.y), -0.5f * (Zt.x - Zc.x));
            const float2 P = cmul(Fk, Fv);
            acc[k2].x += P.x; acc[k2].y += P.y;
        }
        __builtin_amdgcn_sched_barrier(0);  // next r's writes stay after reads
    }
    float2* FsB = Fs + ((size_t)b << 10);
#pragma unroll
    for (int k2 = 0; k2 < 32; ++k2) {
        atomicAdd(&FsB[(k2 << 5) + t].x, acc[k2].x);
        atomicAdd(&FsB[(k2 << 5) + t].y, acc[k2].y);
    }
}

// ===================== register-FFT retrieve kernel ========================
#define RETR_ROWS 4
__global__ __launch_bounds__(128) void retrieve_kernel(
    const unsigned int* __restrict__ QR,
    const float2* __restrict__ Fs, const float* __restrict__ x, float* __restrict__ out)
{
    // per-row transpose buffer, pad 33 (row stride 33 float2) -> conflict-free
    __shared__ __align__(16) float2 T[RETR_ROWS][33 * 32];
    const int tid = threadIdx.x;
    const int lr = tid >> 5;     // local row 0..3
    const int t  = tid & 31;     // lane within row = n2 / k1 / n1 role
    const int row = blockIdx.x * RETR_ROWS + lr;
    const int b = row >> 12;
    const size_t base = (size_t)row << 10;
    float2* Tr = T[lr];

    // ---- load z[n1] = Q + i*R at n = 32*n1 + t (interleaved u32) ---------
    float2 z[32];
    const unsigned int* src = QR + base;
#pragma unroll
    for (int n1 = 0; n1 < 32; ++n1) {
        const unsigned int u = src[(n1 << 5) + t];
        const __half2 hv = *(const __half2*)&u;   // {Q, R}
        z[br5(n1)] = make_float2(__half2float(hv.x), __half2float(hv.y));
    }
    fft32<0>(z);                     // A[k1] over n1 (natural order)

    // ---- middle twiddle W1024^{-t*k1}: sincos once + recurrence ----------
    float sn_, cs_;
    __sincosf((PI_F / 512.0f) * (float)t, &sn_, &cs_);
    {
        const float2 w1 = make_float2(cs_, -sn_);
        float2 tw = make_float2(1.0f, 0.0f);
#pragma unroll
        for (int k1 = 0; k1 < 32; ++k1) { z[k1] = cmul(z[k1], tw); tw = cmul(tw, w1); }
    }

    // ---- transpose #1: write [k1][t], read [t][n2] (bitrev into regs) ----
#pragma unroll
    for (int k1 = 0; k1 < 32; ++k1) Tr[33 * k1 + t] = z[k1];
    __syncthreads();
#pragma unroll
    for (int n2 = 0; n2 < 32; ++n2) z[br5(n2)] = Tr[33 * t + n2];
    fft32<0>(z);                     // z[k2] = Z[t + 32*k2]
    __syncthreads();                 // WAR: transpose reads done

    // ---- mirror round: Z -> LDS [k2][t]; read Z[1024-j] from mirror ------
#pragma unroll
    for (int k2 = 0; k2 < 32; ++k2) Tr[33 * k2 + t] = z[k2];
    __syncthreads();

    float2 h[32];
    const float2* FsB = Fs + ((size_t)b << 10);
    const int mc = (32 - t) & 31;
    const int me = (t == 0) ? 1 : 0;   // t=0 mirrors onto itself, shifted row
#pragma unroll
    for (int k2 = 0; k2 < 32; ++k2) {
        const int ma = (31 - k2 + me) & 31;
        float2 Zc = Tr[33 * ma + mc];
        Zc.y = -Zc.y;                  // conj(Z[1024-j])
        const float2 Zt = z[k2];       // Z[j], j = t + 32*k2
        const float2 Fq = make_float2(0.5f * (Zt.x + Zc.x), 0.5f * (Zt.y + Zc.y));
        const float2 Fr = make_float2(0.5f * (Zt.y - Zc.y), -0.5f * (Zt.x - Zc.x));
        const float2 g2 = make_float2(Fq.x - (Fr.x * Fr.x + Fr.y * Fr.y), -Fq.y);
        const float2 Ff = FsB[(k2 << 5) + t];
        h[br5(k2)] = cmul(Ff, g2);     // H[j], bitrev for inverse stage 1
    }

    // ---- inverse: same distribution (k = t mod 32) -> register-local -----
    fft32<1>(h);                     // over k1
    {
        const float2 w1c = make_float2(cs_, sn_);   // W1024^{+n1*t}
        float2 tw = make_float2(1.0f, 0.0f);
#pragma unroll
        for (int n1 = 0; n1 < 32; ++n1) { h[n1] = cmul(h[n1], tw); tw = cmul(tw, w1c); }
    }
    __syncthreads();                 // WAR: mirror reads done before overwrite
#pragma unroll
    for (int n1 = 0; n1 < 32; ++n1) Tr[33 * n1 + t] = h[n1];
    __syncthreads();
#pragma unroll
    for (int k2 = 0; k2 < 32; ++k2) h[br5(k2)] = Tr[33 * t + k2];
    fft32<1>(h);                     // h[n2] = y[t + 32*n2] (unscaled)

    // ---- out = x + real(y)/1024, coalesced (32 consecutive lanes) --------
    const float* xr = x + base;
    float* outr = out + base;
#pragma unroll
    for (int n2 = 0; n2 < 32; ++n2) {
        const int g = (n2 << 5) + t;
        outr[g] = xr[g] + h[n2].x * (1.0f / 1024.0f);
    }
}

extern "C" void kernel_launch(void* const* d_in, const int* in_sizes, int n_in,
                              void* d_out, int out_size, void* d_ws, size_t ws_size,
                              hipStream_t stream) {
    const float* x  = (const float*)d_in[0];
    const float* Wq = (const float*)d_in[1];
    const float* bq = (const float*)d_in[2];
    const float* Wk = (const float*)d_in[3];
    const float* bk = (const float*)d_in[4];
    const float* Wv = (const float*)d_in[5];
    const float* bv = (const float*)d_in[6];
    const float* Wr = (const float*)d_in[7];
    const float* br = (const float*)d_in[8];
    float* out = (float*)d_out;

    // ws: PKV (64MB interleaved __half2), Fs (32KB)
    __half2* PKV = (__half2*)d_ws;
    float2* Fs = (float2*)((char*)d_ws + (size_t)NROWS * D * 4);

    // d_out doubles as fp16 scratch until the final kernel rewrites all of it
    __half* Xh  = (__half*)d_out;
    __half* Whk = (__half*)d_out + (size_t)16 * 1024 * 1024;
    __half* Whv = Whk + (size_t)1024 * 1024;
    __half* Whq = Whv + (size_t)1024 * 1024;
    __half* Whr = Whq + (size_t)1024 * 1024;

    convert_all<<<16384 + 4 * 1024, 256, 0, stream>>>(
        x, Wk, Wv, Wq, Wr, Xh, Whk, Whv, Whq, Whr);

    hipMemsetAsync(Fs, 0, (size_t)BATCH * D * sizeof(float2), stream);

    gemm_mfma2<<<1024, 256, 0, stream>>>(Xh, Whk, bk, Whv, bv, PKV);
    bind_accum_kernel<<<NROWS / (BGRP * BROWS), 256, 0, stream>>>(
        (const unsigned int*)PKV, Fs);
    gemm_mfma2<<<1024, 256, 0, stream>>>(Xh, Whq, bq, Whr, br, PKV);
    retrieve_kernel<<<NROWS / RETR_ROWS, 128, 0, stream>>>(
        (const unsigned int*)PKV, Fs, x, out);
}

// Round 5
// 507.278 us; speedup vs baseline: 1.0577x; 1.0575x over previous
//
#include <hip/hip_runtime.h>
#include <hip/hip_fp16.h>

#define D 1024
#define LOG2D 10
#define S_LEN 4096
#define BATCH 4
#define NROWS (BATCH * S_LEN) /* 16384 */
#define PI_F 3.14159265358979323846f

typedef _Float16 f16x8 __attribute__((ext_vector_type(8)));
typedef float f32x4 __attribute__((ext_vector_type(4)));

__device__ __forceinline__ float2 cmul(float2 a, float2 b) {
    return make_float2(a.x * b.x - a.y * b.y, a.x * b.y + a.y * b.x);
}

__device__ __forceinline__ float fast_tanh(float v) {
    float e = __expf(2.0f * v);
    return 1.0f - 2.0f * __builtin_amdgcn_rcpf(e + 1.0f);
}

__device__ __forceinline__ void g2lds16(const void* g, void* l) {
    __builtin_amdgcn_global_load_lds(
        (const __attribute__((address_space(1))) unsigned int*)g,
        (__attribute__((address_space(3))) unsigned int*)l, 16, 0, 0);
}

// ---------------- fp32 -> fp16 conversion (x and the 4 weight matrices) ----
__global__ __launch_bounds__(256) void convert_all(
    const float* __restrict__ x,
    const float* __restrict__ w0, const float* __restrict__ w1,
    const float* __restrict__ w2, const float* __restrict__ w3,
    __half* __restrict__ xh,
    __half* __restrict__ h0, __half* __restrict__ h1,
    __half* __restrict__ h2, __half* __restrict__ h3)
{
    const int b = blockIdx.x;
    const float* s;
    __half* d;
    int li;
    if (b < 16384) { s = x; d = xh; li = b; }
    else {
        int t = b - 16384;
        int r = t >> 10;
        li = t & 1023;
        s = (r == 0) ? w0 : (r == 1) ? w1 : (r == 2) ? w2 : w3;
        d = (r == 0) ? h0 : (r == 1) ? h1 : (r == 2) ? h2 : h3;
    }
    const int idx = li * 256 + threadIdx.x;  // float4 index
    float4 v = ((const float4*)s)[idx];
    __half2 lo = __floats2half2_rn(v.x, v.y);
    __half2 hi = __floats2half2_rn(v.z, v.w);
    ((__half2*)d)[2 * idx + 0] = lo;
    ((__half2*)d)[2 * idx + 1] = hi;
}

// ------- Fused dual MFMA GEMM (round-1 proven structure, 89-91 us) --------
// O = {tanh(Xh*W0^T+b0), tanh(Xh*W1^T+b1)} stored INTERLEAVED as __half2.
// 128x128 tile, BK=64 (16 k-tiles, 64 MFMA per barrier pair), 256 thr.
// LDS [row][64] halves, 8 chunks of 16B per row, chunk q stored at slot
// q ^ (row&7) -> global_load_lds stays lane-contiguous, ds_read_b128 2-way max.
// XCD-swizzled block mapping for L2 locality.
__global__ __launch_bounds__(256, 2) void gemm_mfma2(
    const __half* __restrict__ Xh,
    const __half* __restrict__ W0, const float* __restrict__ b0,
    const __half* __restrict__ W1, const float* __restrict__ b1,
    __half2* __restrict__ KV)
{
    const int idx = blockIdx.x;
    const int xcd = idx & 7;
    const int j = idx >> 3;           // 0..127
    const int n0 = (j & 7) * 128;
    const int m0 = (xcd * 16 + (j >> 3)) * 128;

    __shared__ __align__(16) __half As[128 * 64];
    __shared__ __align__(16) __half B0s[128 * 64];
    __shared__ __align__(16) __half B1s[128 * 64];

    const int tid = threadIdx.x;
    const int wave = tid >> 6;
    const int lane = tid & 63;

    // staging: one g2lds = 64 lanes x 16B = 8 rows x 8 chunks.
    const int srow = lane >> 3;
    const int schunk = (lane & 7) ^ (lane >> 3);

    const __half* gA[4];
    const __half* gB0[4];
    const __half* gB1[4];
    int loff[4];
#pragma unroll
    for (int c = 0; c < 4; ++c) {
        const int rbase = wave * 32 + c * 8;         // multiple of 8
        gA[c]  = Xh + (size_t)(m0 + rbase + srow) * 1024 + schunk * 8;
        gB0[c] = W0 + (size_t)(n0 + rbase + srow) * 1024 + schunk * 8;
        gB1[c] = W1 + (size_t)(n0 + rbase + srow) * 1024 + schunk * 8;
        loff[c] = rbase * 64;                         // half units
    }

    const int wm = (wave & 1) * 64;
    const int wn = (wave >> 1) * 64;
    const int quad = lane >> 4;
    const int l15 = lane & 15;

    // frag read offsets: row R, k-slice kk (0/1): chunk c=(kk<<2)|quad at
    // slot c ^ (R&7); R&7 = l15&7 here (wm, i*16 are multiples of 8).
    int aoff[2][4], boff[2][4];
#pragma unroll
    for (int kk = 0; kk < 2; ++kk)
#pragma unroll
        for (int i = 0; i < 4; ++i) {
            const int Ra = wm + i * 16 + l15;
            aoff[kk][i] = Ra * 64 + ((((kk << 2) | quad)) ^ (l15 & 7)) * 8;
            const int Rb = wn + i * 16 + l15;
            boff[kk][i] = Rb * 64 + ((((kk << 2) | quad)) ^ (l15 & 7)) * 8;
        }

    f32x4 acc0[4][4], acc1[4][4];
#pragma unroll
    for (int i = 0; i < 4; ++i)
#pragma unroll
        for (int jj = 0; jj < 4; ++jj) {
            acc0[i][jj] = (f32x4){0.f, 0.f, 0.f, 0.f};
            acc1[i][jj] = (f32x4){0.f, 0.f, 0.f, 0.f};
        }

    for (int kt = 0; kt < 16; ++kt) {
        const int kh = kt * 64;
        __syncthreads();
#pragma unroll
        for (int c = 0; c < 4; ++c) {
            g2lds16(gA[c] + kh,  As  + loff[c]);
            g2lds16(gB0[c] + kh, B0s + loff[c]);
            g2lds16(gB1[c] + kh, B1s + loff[c]);
        }
        __syncthreads();

#pragma unroll
        for (int kk = 0; kk < 2; ++kk) {
            f16x8 af[4], bf0[4], bf1[4];
#pragma unroll
            for (int i = 0; i < 4; ++i) af[i] = *(const f16x8*)(As + aoff[kk][i]);
#pragma unroll
            for (int jj = 0; jj < 4; ++jj) {
                bf0[jj] = *(const f16x8*)(B0s + boff[kk][jj]);
                bf1[jj] = *(const f16x8*)(B1s + boff[kk][jj]);
            }
#pragma unroll
            for (int i = 0; i < 4; ++i)
#pragma unroll
                for (int jj = 0; jj < 4; ++jj) {
                    acc0[i][jj] = __builtin_amdgcn_mfma_f32_16x16x32_f16(af[i], bf0[jj], acc0[i][jj], 0, 0, 0);
                    acc1[i][jj] = __builtin_amdgcn_mfma_f32_16x16x32_f16(af[i], bf1[jj], acc1[i][jj], 0, 0, 0);
                }
        }
    }

    // epilogue: C/D frag mapping col=lane&15, row=quad*4+reg; interleaved pair
#pragma unroll
    for (int jj = 0; jj < 4; ++jj) {
        const int n = n0 + wn + jj * 16 + l15;
        const float bv0 = b0[n];
        const float bv1 = b1[n];
#pragma unroll
        for (int i = 0; i < 4; ++i) {
            const int mbase = m0 + wm + i * 16 + quad * 4;
#pragma unroll
            for (int r = 0; r < 4; ++r) {
                const __half h0 = __float2half(fast_tanh(acc0[i][jj][r] + bv0));
                const __half h1 = __float2half(fast_tanh(acc1[i][jj][r] + bv1));
                KV[(size_t)(mbase + r) * 1024 + n] = __halves2half2(h0, h1);
            }
        }
    }
}

// ================= register FFT-32 building blocks (proven) ================
__device__ constexpr int br5(int i) {
    return ((i & 1) << 4) | ((i & 2) << 2) | (i & 4) | ((i & 8) >> 2) | ((i & 16) >> 4);
}

// W32^k twiddles as compile-time constants (k static after unroll).
// INV=0: e^{-2pi i k/32}; INV=1: conjugate.
template<int INV>
__device__ __forceinline__ float2 w32c(int k) {
    constexpr float C[16] = {
        1.0f, 0.98078528f, 0.92387953f, 0.83146961f,
        0.70710678f, 0.55557023f, 0.38268343f, 0.19509032f,
        0.0f, -0.19509032f, -0.38268343f, -0.55557023f,
        -0.70710678f, -0.83146961f, -0.92387953f, -0.98078528f};
    constexpr float Sn[16] = {
        0.0f, 0.19509032f, 0.38268343f, 0.55557023f,
        0.70710678f, 0.83146961f, 0.92387953f, 0.98078528f,
        1.0f, 0.98078528f, 0.92387953f, 0.83146961f,
        0.70710678f, 0.55557023f, 0.38268343f, 0.19509032f};
    return make_float2(C[k], INV ? Sn[k] : -Sn[k]);
}

// In-register 32-point FFT. Input in registers bit-reversed, output natural.
template<int INV>
__device__ __forceinline__ void fft32(float2* z) {
#pragma unroll
    for (int s = 0; s < 5; ++s) {
#pragma unroll
        for (int j = 0; j < 16; ++j) {
            const int half = 1 << s;
            const int blk = j >> s;
            const int off = j & (half - 1);
            const int i0 = (blk << (s + 1)) + off;
            const int i1 = i0 + half;
            const float2 w = w32c<INV>(off << (4 - s));
            const float2 v = cmul(z[i1], w);
            z[i1] = make_float2(z[i0].x - v.x, z[i0].y - v.y);
            z[i0] = make_float2(z[i0].x + v.x, z[i0].y + v.y);
        }
    }
}

// ================= register-FFT bind kernel (forward only) =================
// Interleaved KV input: lane t loads z[n1] = KV[32*n1 + t] directly from
// global. Per-thread state = z[32] only (~95 VGPR, NO spill — round-4's
// 84MB scratch traffic came from acc[32]+z[32] > 128-VGPR cap).
// Row products accumulate into a block-shared accS[1024] via LDS float
// atomics (ds_add_f32, fire-and-forget, distinct addr per lane in group);
// one global atomicAdd pass per block at the end (8.4M -> 1M atomics).
// Transposes are intra-wave (group = half-wave): DS pipe in-order within a
// wave -> no __syncthreads; sched_barrier(0) pins compiler ordering.
#define BGRP 8
#define BROWS 4
__global__ __launch_bounds__(256) void bind_accum_kernel(
    const unsigned int* __restrict__ KV, float2* __restrict__ Fs)
{
    __shared__ float2 T[BGRP][33 * 32];
    __shared__ float2 accS[1024];
    const int tid = threadIdx.x;
    const int grp = tid >> 5;
    const int t = tid & 31;
    const int row0 = blockIdx.x * (BGRP * BROWS) + grp * BROWS;
    const int b = (blockIdx.x * (BGRP * BROWS)) >> 12;  // 32-row chunks never straddle batches
    float2* Tr = T[grp];

    // zero the shared accumulator
#pragma unroll
    for (int i = 0; i < 4; ++i) accS[tid + (i << 8)] = make_float2(0.f, 0.f);
    __syncthreads();

    float sn_, cs_;
    __sincosf((PI_F / 512.0f) * (float)t, &sn_, &cs_);
    const float2 w1 = make_float2(cs_, -sn_);
    const int mc = (32 - t) & 31;
    const int me = (t == 0) ? 1 : 0;

    for (int r = 0; r < BROWS; ++r) {
        const unsigned int* src = KV + ((size_t)(row0 + r) << 10);
        float2 z[32];
#pragma unroll
        for (int n1 = 0; n1 < 32; ++n1) {
            const unsigned int u = src[(n1 << 5) + t];
            const __half2 hv = *(const __half2*)&u;   // {K, V}
            z[br5(n1)] = make_float2(__half2float(hv.x), __half2float(hv.y));
        }
        fft32<0>(z);                 // A[k1] over n1
        {
            float2 tw = make_float2(1.0f, 0.0f);
#pragma unroll
            for (int k1 = 0; k1 < 32; ++k1) { z[k1] = cmul(z[k1], tw); tw = cmul(tw, w1); }
        }
        // transpose: write [k1][t], read [t][n2] (cross-lane, same wave)
#pragma unroll
        for (int k1 = 0; k1 < 32; ++k1) Tr[33 * k1 + t] = z[k1];
        __builtin_amdgcn_sched_barrier(0);
#pragma unroll
        for (int n2 = 0; n2 < 32; ++n2) z[br5(n2)] = Tr[33 * t + n2];
        fft32<0>(z);                 // Z[t + 32*k2]
        // mirror round: Z -> LDS [k2][t]; read conj(Z[1024-j]) cross-lane
#pragma unroll
        for (int k2 = 0; k2 < 32; ++k2) Tr[33 * k2 + t] = z[k2];
        __builtin_amdgcn_sched_barrier(0);
#pragma unroll
        for (int k2 = 0; k2 < 32; ++k2) {
            const int ma = (31 - k2 + me) & 31;
            float2 Zc = Tr[33 * ma + mc];
            Zc.y = -Zc.y;              // conj(Z[1024-j])
            const float2 Zt = z[k2];   // Z[j], j = t + 32*k2
            const float2 Fk = make_float2(0.5f * (Zt.x + Zc.x), 0.5f * (Zt.y + Zc.y));
            const float2 Fv = make_float2(0.5f * (Zt.y - Zc.y), -0.5f * (Zt.x - Zc.x));
            const float2 P = cmul(Fk, Fv);
            atomicAdd(&accS[(k2 << 5) + t].x, P.x);
            atomicAdd(&accS[(k2 << 5) + t].y, P.y);
        }
        __builtin_amdgcn_sched_barrier(0);  // next r's writes stay after reads
    }
    __syncthreads();
    float2* FsB = Fs + ((size_t)b << 10);
#pragma unroll
    for (int i = 0; i < 4; ++i) {
        const int j2 = tid + (i << 8);
        const float2 v = accS[j2];
        atomicAdd(&FsB[j2].x, v.x);
        atomicAdd(&FsB[j2].y, v.y);
    }
}

// ===================== register-FFT retrieve kernel ========================
#define RETR_ROWS 4
__global__ __launch_bounds__(128) void retrieve_kernel(
    const unsigned int* __restrict__ QR,
    const float2* __restrict__ Fs, const float* __restrict__ x, float* __restrict__ out)
{
    // per-row transpose buffer, pad 33 (row stride 33 float2) -> conflict-free
    __shared__ __align__(16) float2 T[RETR_ROWS][33 * 32];
    const int tid = threadIdx.x;
    const int lr = tid >> 5;     // local row 0..3
    const int t  = tid & 31;     // lane within row = n2 / k1 / n1 role
    const int row = blockIdx.x * RETR_ROWS + lr;
    const int b = row >> 12;
    const size_t base = (size_t)row << 10;
    float2* Tr = T[lr];

    // ---- load z[n1] = Q + i*R at n = 32*n1 + t (interleaved u32) ---------
    float2 z[32];
    const unsigned int* src = QR + base;
#pragma unroll
    for (int n1 = 0; n1 < 32; ++n1) {
        const unsigned int u = src[(n1 << 5) + t];
        const __half2 hv = *(const __half2*)&u;   // {Q, R}
        z[br5(n1)] = make_float2(__half2float(hv.x), __half2float(hv.y));
    }
    fft32<0>(z);                     // A[k1] over n1 (natural order)

    // ---- middle twiddle W1024^{-t*k1}: sincos once + recurrence ----------
    float sn_, cs_;
    __sincosf((PI_F / 512.0f) * (float)t, &sn_, &cs_);
    {
        const float2 w1 = make_float2(cs_, -sn_);
        float2 tw = make_float2(1.0f, 0.0f);
#pragma unroll
        for (int k1 = 0; k1 < 32; ++k1) { z[k1] = cmul(z[k1], tw); tw = cmul(tw, w1); }
    }

    // ---- transpose #1: write [k1][t], read [t][n2] (bitrev into regs) ----
#pragma unroll
    for (int k1 = 0; k1 < 32; ++k1) Tr[33 * k1 + t] = z[k1];
    __syncthreads();
#pragma unroll
    for (int n2 = 0; n2 < 32; ++n2) z[br5(n2)] = Tr[33 * t + n2];
    fft32<0>(z);                     // z[k2] = Z[t + 32*k2]
    __syncthreads();                 // WAR: transpose reads done

    // ---- mirror round: Z -> LDS [k2][t]; read Z[1024-j] from mirror ------
#pragma unroll
    for (int k2 = 0; k2 < 32; ++k2) Tr[33 * k2 + t] = z[k2];
    __syncthreads();

    float2 h[32];
    const float2* FsB = Fs + ((size_t)b << 10);
    const int mc = (32 - t) & 31;
    const int me = (t == 0) ? 1 : 0;   // t=0 mirrors onto itself, shifted row
#pragma unroll
    for (int k2 = 0; k2 < 32; ++k2) {
        const int ma = (31 - k2 + me) & 31;
        float2 Zc = Tr[33 * ma + mc];
        Zc.y = -Zc.y;                  // conj(Z[1024-j])
        const float2 Zt = z[k2];       // Z[j], j = t + 32*k2
        const float2 Fq = make_float2(0.5f * (Zt.x + Zc.x), 0.5f * (Zt.y + Zc.y));
        const float2 Fr = make_float2(0.5f * (Zt.y - Zc.y), -0.5f * (Zt.x - Zc.x));
        const float2 g2 = make_float2(Fq.x - (Fr.x * Fr.x + Fr.y * Fr.y), -Fq.y);
        const float2 Ff = FsB[(k2 << 5) + t];
        h[br5(k2)] = cmul(Ff, g2);     // H[j], bitrev for inverse stage 1
    }

    // ---- inverse: same distribution (k = t mod 32) -> register-local -----
    fft32<1>(h);                     // over k1
    {
        const float2 w1c = make_float2(cs_, sn_);   // W1024^{+n1*t}
        float2 tw = make_float2(1.0f, 0.0f);
#pragma unroll
        for (int n1 = 0; n1 < 32; ++n1) { h[n1] = cmul(h[n1], tw); tw = cmul(tw, w1c); }
    }
    __syncthreads();                 // WAR: mirror reads done before overwrite
#pragma unroll
    for (int n1 = 0; n1 < 32; ++n1) Tr[33 * n1 + t] = h[n1];
    __syncthreads();
#pragma unroll
    for (int k2 = 0; k2 < 32; ++k2) h[br5(k2)] = Tr[33 * t + k2];
    fft32<1>(h);                     // h[n2] = y[t + 32*n2] (unscaled)

    // ---- out = x + real(y)/1024, coalesced (32 consecutive lanes) --------
    const float* xr = x + base;
    float* outr = out + base;
#pragma unroll
    for (int n2 = 0; n2 < 32; ++n2) {
        const int g = (n2 << 5) + t;
        outr[g] = xr[g] + h[n2].x * (1.0f / 1024.0f);
    }
}

extern "C" void kernel_launch(void* const* d_in, const int* in_sizes, int n_in,
                              void* d_out, int out_size, void* d_ws, size_t ws_size,
                              hipStream_t stream) {
    const float* x  = (const float*)d_in[0];
    const float* Wq = (const float*)d_in[1];
    const float* bq = (const float*)d_in[2];
    const float* Wk = (const float*)d_in[3];
    const float* bk = (const float*)d_in[4];
    const float* Wv = (const float*)d_in[5];
    const float* bv = (const float*)d_in[6];
    const float* Wr = (const float*)d_in[7];
    const float* br = (const float*)d_in[8];
    float* out = (float*)d_out;

    // ws: PKV (64MB interleaved __half2), Fs (32KB)
    __half2* PKV = (__half2*)d_ws;
    float2* Fs = (float2*)((char*)d_ws + (size_t)NROWS * D * 4);

    // d_out doubles as fp16 scratch until the final kernel rewrites all of it
    __half* Xh  = (__half*)d_out;
    __half* Whk = (__half*)d_out + (size_t)16 * 1024 * 1024;
    __half* Whv = Whk + (size_t)1024 * 1024;
    __half* Whq = Whv + (size_t)1024 * 1024;
    __half* Whr = Whq + (size_t)1024 * 1024;

    convert_all<<<16384 + 4 * 1024, 256, 0, stream>>>(
        x, Wk, Wv, Wq, Wr, Xh, Whk, Whv, Whq, Whr);

    hipMemsetAsync(Fs, 0, (size_t)BATCH * D * sizeof(float2), stream);

    gemm_mfma2<<<1024, 256, 0, stream>>>(Xh, Whk, bk, Whv, bv, PKV);
    bind_accum_kernel<<<NROWS / (BGRP * BROWS), 256, 0, stream>>>(
        (const unsigned int*)PKV, Fs);
    gemm_mfma2<<<1024, 256, 0, stream>>>(Xh, Whq, bq, Whr, br, PKV);
    retrieve_kernel<<<NROWS / RETR_ROWS, 128, 0, stream>>>(
        (const unsigned int*)PKV, Fs, x, out);
}

// Round 6
// 420.696 us; speedup vs baseline: 1.2754x; 1.2058x over previous
//
#include <hip/hip_runtime.h>
#include <hip/hip_fp16.h>

#define D 1024
#define LOG2D 10
#define S_LEN 4096
#define BATCH 4
#define NROWS (BATCH * S_LEN) /* 16384 */
#define PI_F 3.14159265358979323846f

typedef _Float16 f16x8 __attribute__((ext_vector_type(8)));
typedef float f32x4 __attribute__((ext_vector_type(4)));

__device__ __forceinline__ float2 cmul(float2 a, float2 b) {
    return make_float2(a.x * b.x - a.y * b.y, a.x * b.y + a.y * b.x);
}

__device__ __forceinline__ float fast_tanh(float v) {
    float e = __expf(2.0f * v);
    return 1.0f - 2.0f * __builtin_amdgcn_rcpf(e + 1.0f);
}

__device__ __forceinline__ void g2lds16(const void* g, void* l) {
    __builtin_amdgcn_global_load_lds(
        (const __attribute__((address_space(1))) unsigned int*)g,
        (__attribute__((address_space(3))) unsigned int*)l, 16, 0, 0);
}

// ---------------- fp32 -> fp16 conversion (x and the 4 weight matrices) ----
__global__ __launch_bounds__(256) void convert_all(
    const float* __restrict__ x,
    const float* __restrict__ w0, const float* __restrict__ w1,
    const float* __restrict__ w2, const float* __restrict__ w3,
    __half* __restrict__ xh,
    __half* __restrict__ h0, __half* __restrict__ h1,
    __half* __restrict__ h2, __half* __restrict__ h3)
{
    const int b = blockIdx.x;
    const float* s;
    __half* d;
    int li;
    if (b < 16384) { s = x; d = xh; li = b; }
    else {
        int t = b - 16384;
        int r = t >> 10;
        li = t & 1023;
        s = (r == 0) ? w0 : (r == 1) ? w1 : (r == 2) ? w2 : w3;
        d = (r == 0) ? h0 : (r == 1) ? h1 : (r == 2) ? h2 : h3;
    }
    const int idx = li * 256 + threadIdx.x;  // float4 index
    float4 v = ((const float4*)s)[idx];
    __half2 lo = __floats2half2_rn(v.x, v.y);
    __half2 hi = __floats2half2_rn(v.z, v.w);
    ((__half2*)d)[2 * idx + 0] = lo;
    ((__half2*)d)[2 * idx + 1] = hi;
}

// ------- Fused dual MFMA GEMM (round-1 proven structure, 89-91 us) --------
// O = {tanh(Xh*W0^T+b0), tanh(Xh*W1^T+b1)} stored INTERLEAVED as __half2.
// 128x128 tile, BK=64 (16 k-tiles, 64 MFMA per barrier pair), 256 thr.
// LDS [row][64] halves, 8 chunks of 16B per row, chunk q stored at slot
// q ^ (row&7) -> global_load_lds stays lane-contiguous, ds_read_b128 2-way max.
// XCD-swizzled block mapping for L2 locality.
__global__ __launch_bounds__(256, 2) void gemm_mfma2(
    const __half* __restrict__ Xh,
    const __half* __restrict__ W0, const float* __restrict__ b0,
    const __half* __restrict__ W1, const float* __restrict__ b1,
    __half2* __restrict__ KV)
{
    const int idx = blockIdx.x;
    const int xcd = idx & 7;
    const int j = idx >> 3;           // 0..127
    const int n0 = (j & 7) * 128;
    const int m0 = (xcd * 16 + (j >> 3)) * 128;

    __shared__ __align__(16) __half As[128 * 64];
    __shared__ __align__(16) __half B0s[128 * 64];
    __shared__ __align__(16) __half B1s[128 * 64];

    const int tid = threadIdx.x;
    const int wave = tid >> 6;
    const int lane = tid & 63;

    // staging: one g2lds = 64 lanes x 16B = 8 rows x 8 chunks.
    const int srow = lane >> 3;
    const int schunk = (lane & 7) ^ (lane >> 3);

    const __half* gA[4];
    const __half* gB0[4];
    const __half* gB1[4];
    int loff[4];
#pragma unroll
    for (int c = 0; c < 4; ++c) {
        const int rbase = wave * 32 + c * 8;         // multiple of 8
        gA[c]  = Xh + (size_t)(m0 + rbase + srow) * 1024 + schunk * 8;
        gB0[c] = W0 + (size_t)(n0 + rbase + srow) * 1024 + schunk * 8;
        gB1[c] = W1 + (size_t)(n0 + rbase + srow) * 1024 + schunk * 8;
        loff[c] = rbase * 64;                         // half units
    }

    const int wm = (wave & 1) * 64;
    const int wn = (wave >> 1) * 64;
    const int quad = lane >> 4;
    const int l15 = lane & 15;

    // frag read offsets: row R, k-slice kk (0/1): chunk c=(kk<<2)|quad at
    // slot c ^ (R&7); R&7 = l15&7 here (wm, i*16 are multiples of 8).
    int aoff[2][4], boff[2][4];
#pragma unroll
    for (int kk = 0; kk < 2; ++kk)
#pragma unroll
        for (int i = 0; i < 4; ++i) {
            const int Ra = wm + i * 16 + l15;
            aoff[kk][i] = Ra * 64 + ((((kk << 2) | quad)) ^ (l15 & 7)) * 8;
            const int Rb = wn + i * 16 + l15;
            boff[kk][i] = Rb * 64 + ((((kk << 2) | quad)) ^ (l15 & 7)) * 8;
        }

    f32x4 acc0[4][4], acc1[4][4];
#pragma unroll
    for (int i = 0; i < 4; ++i)
#pragma unroll
        for (int jj = 0; jj < 4; ++jj) {
            acc0[i][jj] = (f32x4){0.f, 0.f, 0.f, 0.f};
            acc1[i][jj] = (f32x4){0.f, 0.f, 0.f, 0.f};
        }

    for (int kt = 0; kt < 16; ++kt) {
        const int kh = kt * 64;
        __syncthreads();
#pragma unroll
        for (int c = 0; c < 4; ++c) {
            g2lds16(gA[c] + kh,  As  + loff[c]);
            g2lds16(gB0[c] + kh, B0s + loff[c]);
            g2lds16(gB1[c] + kh, B1s + loff[c]);
        }
        __syncthreads();

#pragma unroll
        for (int kk = 0; kk < 2; ++kk) {
            f16x8 af[4], bf0[4], bf1[4];
#pragma unroll
            for (int i = 0; i < 4; ++i) af[i] = *(const f16x8*)(As + aoff[kk][i]);
#pragma unroll
            for (int jj = 0; jj < 4; ++jj) {
                bf0[jj] = *(const f16x8*)(B0s + boff[kk][jj]);
                bf1[jj] = *(const f16x8*)(B1s + boff[kk][jj]);
            }
#pragma unroll
            for (int i = 0; i < 4; ++i)
#pragma unroll
                for (int jj = 0; jj < 4; ++jj) {
                    acc0[i][jj] = __builtin_amdgcn_mfma_f32_16x16x32_f16(af[i], bf0[jj], acc0[i][jj], 0, 0, 0);
                    acc1[i][jj] = __builtin_amdgcn_mfma_f32_16x16x32_f16(af[i], bf1[jj], acc1[i][jj], 0, 0, 0);
                }
        }
    }

    // epilogue: C/D frag mapping col=lane&15, row=quad*4+reg; interleaved pair
#pragma unroll
    for (int jj = 0; jj < 4; ++jj) {
        const int n = n0 + wn + jj * 16 + l15;
        const float bv0 = b0[n];
        const float bv1 = b1[n];
#pragma unroll
        for (int i = 0; i < 4; ++i) {
            const int mbase = m0 + wm + i * 16 + quad * 4;
#pragma unroll
            for (int r = 0; r < 4; ++r) {
                const __half h0 = __float2half(fast_tanh(acc0[i][jj][r] + bv0));
                const __half h1 = __float2half(fast_tanh(acc1[i][jj][r] + bv1));
                KV[(size_t)(mbase + r) * 1024 + n] = __halves2half2(h0, h1);
            }
        }
    }
}

// ================= register FFT-32 building blocks (proven) ================
__device__ constexpr int br5(int i) {
    return ((i & 1) << 4) | ((i & 2) << 2) | (i & 4) | ((i & 8) >> 2) | ((i & 16) >> 4);
}

// W32^k twiddles as compile-time constants (k static after unroll).
// INV=0: e^{-2pi i k/32}; INV=1: conjugate.
template<int INV>
__device__ __forceinline__ float2 w32c(int k) {
    constexpr float C[16] = {
        1.0f, 0.98078528f, 0.92387953f, 0.83146961f,
        0.70710678f, 0.55557023f, 0.38268343f, 0.19509032f,
        0.0f, -0.19509032f, -0.38268343f, -0.55557023f,
        -0.70710678f, -0.83146961f, -0.92387953f, -0.98078528f};
    constexpr float Sn[16] = {
        0.0f, 0.19509032f, 0.38268343f, 0.55557023f,
        0.70710678f, 0.83146961f, 0.92387953f, 0.98078528f,
        1.0f, 0.98078528f, 0.92387953f, 0.83146961f,
        0.70710678f, 0.55557023f, 0.38268343f, 0.19509032f};
    return make_float2(C[k], INV ? Sn[k] : -Sn[k]);
}

// In-register 32-point FFT. Input in registers bit-reversed, output natural.
template<int INV>
__device__ __forceinline__ void fft32(float2* z) {
#pragma unroll
    for (int s = 0; s < 5; ++s) {
#pragma unroll
        for (int j = 0; j < 16; ++j) {
            const int half = 1 << s;
            const int blk = j >> s;
            const int off = j & (half - 1);
            const int i0 = (blk << (s + 1)) + off;
            const int i1 = i0 + half;
            const float2 w = w32c<INV>(off << (4 - s));
            const float2 v = cmul(z[i1], w);
            z[i1] = make_float2(z[i0].x - v.x, z[i0].y - v.y);
            z[i0] = make_float2(z[i0].x + v.x, z[i0].y + v.y);
        }
    }
}

// ================= register-FFT bind kernel (forward only) =================
// Algebraic simplification: for z = k + iv,  P = Fk*Fv = W(j) + conj(W(-j))
// with W = -i/4 * Z^2 (LANE-LOCAL: no Hermitian unpack, no mirror LDS round).
// Symmetrization commutes with the row-sum, so bind accumulates S = sum(W)
// only; retrieve computes Ff = S[j] + conj(S[-j]) on the fly.
// Single-wave 64-thread blocks (2 groups of 32 lanes), BROWS rows per group;
// acc[32] float2 in regs, z[32] transient; cap (64,2) -> 256 VGPR, no spill.
// NO LDS atomics (round-5's 189us: fp atomicAdd on LDS + same-address lane
// collisions). Tail: shfl_xor(32) pair-reduce, then 2048 global f32 atomics
// per block (the round-0-proven rate).
#define BROWS 4
__global__ __launch_bounds__(64, 2) void bind_accum_kernel(
    const unsigned int* __restrict__ KV, float2* __restrict__ Fs)
{
    __shared__ float2 T[2][33 * 32];
    const int tid = threadIdx.x;
    const int grp = tid >> 5;
    const int t = tid & 31;
    const int row0 = blockIdx.x * (2 * BROWS) + grp * BROWS;
    const int b = row0 >> 12;   // 8-row chunks never straddle batches
    float2* Tr = T[grp];

    float sn_, cs_;
    __sincosf((PI_F / 512.0f) * (float)t, &sn_, &cs_);
    const float2 w1 = make_float2(cs_, -sn_);

    float2 acc[32];
#pragma unroll
    for (int i = 0; i < 32; ++i) acc[i] = make_float2(0.f, 0.f);

    for (int r = 0; r < BROWS; ++r) {
        const unsigned int* src = KV + ((size_t)(row0 + r) << 10);
        float2 z[32];
#pragma unroll
        for (int n1 = 0; n1 < 32; ++n1) {
            const unsigned int u = src[(n1 << 5) + t];
            const __half2 hv = *(const __half2*)&u;   // {K, V}
            z[br5(n1)] = make_float2(__half2float(hv.x), __half2float(hv.y));
        }
        fft32<0>(z);                 // A[k1] over n1
        {
            float2 tw = make_float2(1.0f, 0.0f);
#pragma unroll
            for (int k1 = 0; k1 < 32; ++k1) { z[k1] = cmul(z[k1], tw); tw = cmul(tw, w1); }
        }
        // transpose: write [k1][t], read [t][n2] (cross-lane, same wave ->
        // DS pipe in-order; sched_barrier pins compiler ordering)
#pragma unroll
        for (int k1 = 0; k1 < 32; ++k1) Tr[33 * k1 + t] = z[k1];
        __builtin_amdgcn_sched_barrier(0);
#pragma unroll
        for (int n2 = 0; n2 < 32; ++n2) z[br5(n2)] = Tr[33 * t + n2];
        fft32<0>(z);                 // Z[j], j = t + 32*k2
        __builtin_amdgcn_sched_barrier(0);  // next r's Tr writes stay after reads
        // W = -i/4 * Z^2 = (x*y/2, (y^2 - x^2)/4), accumulate
#pragma unroll
        for (int k2 = 0; k2 < 32; ++k2) {
            const float zx = z[k2].x, zy = z[k2].y;
            acc[k2].x = __builtin_fmaf(zx * zy, 0.5f, acc[k2].x);
            acc[k2].y += 0.25f * (zy * zy - zx * zx);
        }
    }

    // pair-reduce the two half-wave groups (same j set, different rows)
    float2* FsB = Fs + ((size_t)b << 10);
#pragma unroll
    for (int k2 = 0; k2 < 32; ++k2) {
        const float sx = acc[k2].x + __shfl_xor(acc[k2].x, 32);
        const float sy = acc[k2].y + __shfl_xor(acc[k2].y, 32);
        if (grp == 0) {
            atomicAdd(&FsB[(k2 << 5) + t].x, sx);
            atomicAdd(&FsB[(k2 << 5) + t].y, sy);
        }
    }
}

// ===================== register-FFT retrieve kernel ========================
#define RETR_ROWS 4
__global__ __launch_bounds__(128) void retrieve_kernel(
    const unsigned int* __restrict__ QR,
    const float2* __restrict__ Fs, const float* __restrict__ x, float* __restrict__ out)
{
    // per-row transpose buffer, pad 33 (row stride 33 float2) -> conflict-free
    __shared__ __align__(16) float2 T[RETR_ROWS][33 * 32];
    const int tid = threadIdx.x;
    const int lr = tid >> 5;     // local row 0..3
    const int t  = tid & 31;     // lane within row = n2 / k1 / n1 role
    const int row = blockIdx.x * RETR_ROWS + lr;
    const int b = row >> 12;
    const size_t base = (size_t)row << 10;
    float2* Tr = T[lr];

    // ---- load z[n1] = Q + i*R at n = 32*n1 + t (interleaved u32) ---------
    float2 z[32];
    const unsigned int* src = QR + base;
#pragma unroll
    for (int n1 = 0; n1 < 32; ++n1) {
        const unsigned int u = src[(n1 << 5) + t];
        const __half2 hv = *(const __half2*)&u;   // {Q, R}
        z[br5(n1)] = make_float2(__half2float(hv.x), __half2float(hv.y));
    }
    fft32<0>(z);                     // A[k1] over n1 (natural order)

    // ---- middle twiddle W1024^{-t*k1}: sincos once + recurrence ----------
    float sn_, cs_;
    __sincosf((PI_F / 512.0f) * (float)t, &sn_, &cs_);
    {
        const float2 w1 = make_float2(cs_, -sn_);
        float2 tw = make_float2(1.0f, 0.0f);
#pragma unroll
        for (int k1 = 0; k1 < 32; ++k1) { z[k1] = cmul(z[k1], tw); tw = cmul(tw, w1); }
    }

    // ---- transpose #1: write [k1][t], read [t][n2] (bitrev into regs) ----
#pragma unroll
    for (int k1 = 0; k1 < 32; ++k1) Tr[33 * k1 + t] = z[k1];
    __syncthreads();
#pragma unroll
    for (int n2 = 0; n2 < 32; ++n2) z[br5(n2)] = Tr[33 * t + n2];
    fft32<0>(z);                     // z[k2] = Z[t + 32*k2]
    __syncthreads();                 // WAR: transpose reads done

    // ---- mirror round: Z -> LDS [k2][t]; read Z[1024-j] from mirror ------
#pragma unroll
    for (int k2 = 0; k2 < 32; ++k2) Tr[33 * k2 + t] = z[k2];
    __syncthreads();

    float2 h[32];
    const float2* FsB = Fs + ((size_t)b << 10);
    const int mc = (32 - t) & 31;
    const int me = (t == 0) ? 1 : 0;   // t=0 mirrors onto itself, shifted row
#pragma unroll
    for (int k2 = 0; k2 < 32; ++k2) {
        const int ma = (31 - k2 + me) & 31;
        float2 Zc = Tr[33 * ma + mc];
        Zc.y = -Zc.y;                  // conj(Z[1024-j])
        const float2 Zt = z[k2];       // Z[j], j = t + 32*k2
        const float2 Fq = make_float2(0.5f * (Zt.x + Zc.x), 0.5f * (Zt.y + Zc.y));
        const float2 Fr = make_float2(0.5f * (Zt.y - Zc.y), -0.5f * (Zt.x - Zc.x));
        const float2 g2 = make_float2(Fq.x - (Fr.x * Fr.x + Fr.y * Fr.y), -Fq.y);
        // Fs holds UNSYMMETRIZED S = sum(W); Ff = S[j] + conj(S[-j])
        const int jdx = (k2 << 5) + t;
        const float2 Sf = FsB[jdx];
        const float2 Sm = FsB[(1024 - jdx) & 1023];
        const float2 Ff = make_float2(Sf.x + Sm.x, Sf.y - Sm.y);
        h[br5(k2)] = cmul(Ff, g2);     // H[j], bitrev for inverse stage 1
    }

    // ---- inverse: same distribution (k = t mod 32) -> register-local -----
    fft32<1>(h);                     // over k1
    {
        const float2 w1c = make_float2(cs_, sn_);   // W1024^{+n1*t}
        float2 tw = make_float2(1.0f, 0.0f);
#pragma unroll
        for (int n1 = 0; n1 < 32; ++n1) { h[n1] = cmul(h[n1], tw); tw = cmul(tw, w1c); }
    }
    __syncthreads();                 // WAR: mirror reads done before overwrite
#pragma unroll
    for (int n1 = 0; n1 < 32; ++n1) Tr[33 * n1 + t] = h[n1];
    __syncthreads();
#pragma unroll
    for (int k2 = 0; k2 < 32; ++k2) h[br5(k2)] = Tr[33 * t + k2];
    fft32<1>(h);                     // h[n2] = y[t + 32*n2] (unscaled)

    // ---- out = x + real(y)/1024, coalesced (32 consecutive lanes) --------
    const float* xr = x + base;
    float* outr = out + base;
#pragma unroll
    for (int n2 = 0; n2 < 32; ++n2) {
        const int g = (n2 << 5) + t;
        outr[g] = xr[g] + h[n2].x * (1.0f / 1024.0f);
    }
}

extern "C" void kernel_launch(void* const* d_in, const int* in_sizes, int n_in,
                              void* d_out, int out_size, void* d_ws, size_t ws_size,
                              hipStream_t stream) {
    const float* x  = (const float*)d_in[0];
    const float* Wq = (const float*)d_in[1];
    const float* bq = (const float*)d_in[2];
    const float* Wk = (const float*)d_in[3];
    const float* bk = (const float*)d_in[4];
    const float* Wv = (const float*)d_in[5];
    const float* bv = (const float*)d_in[6];
    const float* Wr = (const float*)d_in[7];
    const float* br = (const float*)d_in[8];
    float* out = (float*)d_out;

    // ws: PKV (64MB interleaved __half2), Fs (32KB)
    __half2* PKV = (__half2*)d_ws;
    float2* Fs = (float2*)((char*)d_ws + (size_t)NROWS * D * 4);

    // d_out doubles as fp16 scratch until the final kernel rewrites all of it
    __half* Xh  = (__half*)d_out;
    __half* Whk = (__half*)d_out + (size_t)16 * 1024 * 1024;
    __half* Whv = Whk + (size_t)1024 * 1024;
    __half* Whq = Whv + (size_t)1024 * 1024;
    __half* Whr = Whq + (size_t)1024 * 1024;

    convert_all<<<16384 + 4 * 1024, 256, 0, stream>>>(
        x, Wk, Wv, Wq, Wr, Xh, Whk, Whv, Whq, Whr);

    hipMemsetAsync(Fs, 0, (size_t)BATCH * D * sizeof(float2), stream);

    gemm_mfma2<<<1024, 256, 0, stream>>>(Xh, Whk, bk, Whv, bv, PKV);
    bind_accum_kernel<<<NROWS / (2 * BROWS), 64, 0, stream>>>(
        (const unsigned int*)PKV, Fs);
    gemm_mfma2<<<1024, 256, 0, stream>>>(Xh, Whq, bq, Whr, br, PKV);
    retrieve_kernel<<<NROWS / RETR_ROWS, 128, 0, stream>>>(
        (const unsigned int*)PKV, Fs, x, out);
}